// Round 16
// baseline (3072.430 us; speedup 1.0000x reference)
//
#include <hip/hip_runtime.h>
#include <stdint.h>

#define DD 256
#define NEDGE 300000
#define NNODE 100000
#define NLAY 9
#define LN_EPS 1e-5f

typedef __attribute__((ext_vector_type(8))) short bf16x8;
typedef __attribute__((ext_vector_type(4))) short s16x4;
typedef __attribute__((ext_vector_type(4))) float f32x4;
typedef __attribute__((ext_vector_type(4))) int i32x4;

static __device__ __forceinline__ short f2bf(float f) {
  union { float f; uint32_t u; } v; v.f = f;
  uint32_t r = (v.u + 0x7FFFu + ((v.u >> 16) & 1u)) >> 16;
  return (short)(uint16_t)r;
}
static __device__ __forceinline__ float bf2f(short s) {
  union { uint32_t u; float f; } v; v.u = ((uint32_t)(uint16_t)s) << 16;
  return v.f;
}
// packed bf16 pair add
static __device__ __forceinline__ int addbf2(int a, int b) {
  const float a0 = bf2f((short)(a & 0xffff)), a1 = bf2f((short)(((uint32_t)a) >> 16));
  const float b0 = bf2f((short)(b & 0xffff)), b1 = bf2f((short)(((uint32_t)b) >> 16));
  const uint16_t r0 = (uint16_t)f2bf(a0 + b0), r1 = (uint16_t)f2bf(a1 + b1);
  return (int)(((uint32_t)r1 << 16) | r0);
}

static __device__ __forceinline__ void gld16(const void* g, void* l) {
  __builtin_amdgcn_global_load_lds((const __attribute__((address_space(1))) void*)g,
                                   (__attribute__((address_space(3))) void*)l, 16, 0, 0);
}

// ---------------------------------------------------------------------------
// Weight pre-transpose + bf16: chunk j = kq*256+col holds W[col][kq*8..+7].
// ---------------------------------------------------------------------------
__global__ void cvtw_kernel(const float* __restrict__ src, short* __restrict__ dst, int nmat) {
  const int total = nmat * 8192;
  for (int j = blockIdx.x * blockDim.x + threadIdx.x; j < total; j += gridDim.x * blockDim.x) {
    const int m = j >> 13;
    const int jj = j & 8191;
    const int col = jj & 255;
    const int kq = jj >> 8;
    const float* s = src + (size_t)m * 65536 + col * 256 + kq * 8;
    const f32x4 u0 = *(const f32x4*)(s);
    const f32x4 u1 = *(const f32x4*)(s + 4);
    bf16x8 o;
#pragma unroll
    for (int q = 0; q < 4; ++q) { o[q] = f2bf(u0[q]); o[q + 4] = f2bf(u1[q]); }
    *(bf16x8*)(dst + (size_t)j * 8) = o;
  }
}

// ---------------------------------------------------------------------------
// Edge MLP v16 — 1024 thr = 16 waves (2M x 8N); tile 64r x 256c; wave 32r x
// 32c; acc[2][2] (8 VGPR). Same 64x256 tile & 1-barrier/K-step schedule as
// v14, but 32 waves/CU resident (2 blocks/CU, launch_bounds(1024,8) caps
// VGPR at 64). LDS: Wslot0 @0, Wslot1 @16384, A/hidden @32768, red @65536
// (4KB: 8 partials/row). Total 69632.
// ---------------------------------------------------------------------------
template<bool A_BF16>
__global__ __launch_bounds__(1024, 8) void edge_kernel(
    const void* __restrict__ Ain, const int* __restrict__ rowmap,
    const short* __restrict__ W1t, const short* __restrict__ W2t,
    const float* __restrict__ B1, const float* __restrict__ B2,
    const float* __restrict__ LG, const float* __restrict__ LB,
    short* __restrict__ OutB, int M) {
  extern __shared__ char smem[];
  char* Abuf = smem + 32768;
  float* redbuf = (float*)(smem + 65536);
  const int tid = threadIdx.x;
  const int lane = tid & 63;
  const int wv = tid >> 6;        // 0..15
  const int wm = wv >> 3, wn = wv & 7;
  const int l15 = lane & 15, lq = lane >> 4;
  const int cbase = wn * 32;
  const int r0 = blockIdx.x * 64;

  auto stageW = [&](const short* Wt, int s, int slot) {
    gld16(Wt + ((size_t)s * 1024 + tid) * 8, smem + slot * 16384 + tid * 16);
  };

  stageW(W1t, 0, 0);

  // stage A tile [kq][row][16B]
  if (A_BF16) {
    const short* A = (const short*)Ain;
#pragma unroll
    for (int j = 0; j < 2; ++j) {
      const int c = tid + 1024 * j;
      const int row = c & 63, kq = c >> 6;
      const int gr = min(r0 + row, M - 1);
      gld16(A + (size_t)gr * DD + kq * 8, Abuf + c * 16);
    }
  } else {
    const float* A = (const float*)Ain;
#pragma unroll
    for (int j = 0; j < 2; ++j) {
      const int c = tid + 1024 * j;
      const int row = c & 63, kq = c >> 6;
      const int gr0 = min(r0 + row, M - 1);
      const int gr = rowmap ? rowmap[gr0] : gr0;
      const f32x4 u0 = *(const f32x4*)(A + (size_t)gr * DD + kq * 8);
      const f32x4 u1 = *(const f32x4*)(A + (size_t)gr * DD + kq * 8 + 4);
      bf16x8 o;
#pragma unroll
      for (int q = 0; q < 4; ++q) { o[q] = f2bf(u0[q]); o[q + 4] = f2bf(u1[q]); }
      *(bf16x8*)(Abuf + c * 16) = o;
    }
  }
  __syncthreads();  // A + W1 slice0 ready

  f32x4 acc[2][2];
#pragma unroll
  for (int mi = 0; mi < 2; ++mi)
#pragma unroll
    for (int ni = 0; ni < 2; ++ni) acc[mi][ni] = (f32x4){0.f, 0.f, 0.f, 0.f};

  // ---------------- GEMM1 ----------------
#pragma unroll
  for (int s = 0; s < 8; ++s) {
    if (s < 7) stageW(W1t, s + 1, (s + 1) & 1);
    else       stageW(W2t, 0, 0);
    const char* wb = smem + (s & 1) * 16384;
    bf16x8 a[2], b[2];
#pragma unroll
    for (int mi = 0; mi < 2; ++mi) {
      const int row = wm * 32 + mi * 16 + l15;
      a[mi] = *(const bf16x8*)(Abuf + (((s * 4 + lq) * 64) + row) * 16);
    }
#pragma unroll
    for (int ni = 0; ni < 2; ++ni)
      b[ni] = *(const bf16x8*)(wb + lq * 4096 + (cbase + ni * 16 + l15) * 16);
#pragma unroll
    for (int ni = 0; ni < 2; ++ni)
#pragma unroll
      for (int mi = 0; mi < 2; ++mi)
        acc[mi][ni] = __builtin_amdgcn_mfma_f32_16x16x32_bf16(b[ni], a[mi], acc[mi][ni], 0, 0, 0);
    __syncthreads();
  }

  // ---- EPI1: bias+relu -> hidden (aliases Abuf; granule-swizzled) ----
  short* hid = (short*)Abuf;
  {
    f32x4 b1q[2];
#pragma unroll
    for (int ni = 0; ni < 2; ++ni)
      b1q[ni] = *(const f32x4*)(B1 + cbase + ni * 16 + lq * 4);
#pragma unroll
    for (int mi = 0; mi < 2; ++mi) {
      const int r = wm * 32 + mi * 16 + l15;
#pragma unroll
      for (int ni = 0; ni < 2; ++ni) {
        const int c4 = cbase + ni * 16 + lq * 4;
        s16x4 o;
#pragma unroll
        for (int i = 0; i < 4; ++i) {
          o[i] = f2bf(fmaxf(acc[mi][ni][i] + b1q[ni][i], 0.f));
          acc[mi][ni][i] = 0.f;
        }
        *(s16x4*)((char*)hid + r * 512 + (((c4 >> 3) ^ (r & 7)) << 4) + (c4 & 7) * 2) = o;
      }
    }
  }
  __syncthreads();  // hidden ready

  // ---------------- GEMM2 ----------------
#pragma unroll
  for (int s = 0; s < 8; ++s) {
    if (s < 7) stageW(W2t, s + 1, (s + 1) & 1);
    const char* wb = smem + (s & 1) * 16384;
    bf16x8 a[2], b[2];
#pragma unroll
    for (int mi = 0; mi < 2; ++mi) {
      const int r = wm * 32 + mi * 16 + l15;
      a[mi] = *(const bf16x8*)((const char*)hid + r * 512 + ((((s * 4 + lq)) ^ (r & 7)) << 4));
    }
#pragma unroll
    for (int ni = 0; ni < 2; ++ni)
      b[ni] = *(const bf16x8*)(wb + lq * 4096 + (cbase + ni * 16 + l15) * 16);
#pragma unroll
    for (int ni = 0; ni < 2; ++ni)
#pragma unroll
      for (int mi = 0; mi < 2; ++mi)
        acc[mi][ni] = __builtin_amdgcn_mfma_f32_16x16x32_bf16(b[ni], a[mi], acc[mi][ni], 0, 0, 0);
    __syncthreads();
  }

  // ---------------- LN ----------------
  f32x4 b2q[2];
#pragma unroll
  for (int ni = 0; ni < 2; ++ni)
    b2q[ni] = *(const f32x4*)(B2 + cbase + ni * 16 + lq * 4);
  float mean_[2], inv_[2];
#pragma unroll
  for (int mi = 0; mi < 2; ++mi) {
    float s1 = 0.f, s2 = 0.f;
#pragma unroll
    for (int ni = 0; ni < 2; ++ni)
#pragma unroll
      for (int i = 0; i < 4; ++i) {
        const float v = acc[mi][ni][i] + b2q[ni][i];
        s1 += v; s2 += v * v;
      }
    s1 += __shfl_xor(s1, 16); s2 += __shfl_xor(s2, 16);
    s1 += __shfl_xor(s1, 32); s2 += __shfl_xor(s2, 32);
    mean_[mi] = s1; inv_[mi] = s2;  // per-wave 32-col partials
  }
  if (lq == 0) {
#pragma unroll
    for (int mi = 0; mi < 2; ++mi) {
      const int r = wm * 32 + mi * 16 + l15;
      redbuf[(r * 8 + wn) * 2 + 0] = mean_[mi];
      redbuf[(r * 8 + wn) * 2 + 1] = inv_[mi];
    }
  }
  __syncthreads();
#pragma unroll
  for (int mi = 0; mi < 2; ++mi) {
    const int r = wm * 32 + mi * 16 + l15;
    float t1 = 0.f, t2 = 0.f;
#pragma unroll
    for (int w = 0; w < 8; ++w) {
      t1 += redbuf[(r * 8 + w) * 2 + 0];
      t2 += redbuf[(r * 8 + w) * 2 + 1];
    }
    const float mean = t1 * (1.f / 256.f);
    const float var = t2 * (1.f / 256.f) - mean * mean;
    mean_[mi] = mean;
    inv_[mi] = rsqrtf(var + LN_EPS);
  }

  f32x4 gq[2], bq[2];
#pragma unroll
  for (int ni = 0; ni < 2; ++ni) {
    gq[ni] = *(const f32x4*)(LG + cbase + ni * 16 + lq * 4);
    bq[ni] = *(const f32x4*)(LB + cbase + ni * 16 + lq * 4);
  }
  short* ob = (short*)Abuf;
#pragma unroll
  for (int mi = 0; mi < 2; ++mi) {
    const int r = wm * 32 + mi * 16 + l15;
#pragma unroll
    for (int ni = 0; ni < 2; ++ni) {
      const int c4 = cbase + ni * 16 + lq * 4;
      s16x4 o;
#pragma unroll
      for (int i = 0; i < 4; ++i)
        o[i] = f2bf((acc[mi][ni][i] + b2q[ni][i] - mean_[mi]) * inv_[mi] * gq[ni][i] + bq[ni][i]);
      *(s16x4*)((char*)ob + r * 512 + (((c4 >> 3) ^ (r & 7)) << 4) + (c4 & 7) * 2) = o;
    }
  }
  __syncthreads();  // ob ready
#pragma unroll
  for (int j = 0; j < 2; ++j) {
    const int gg = tid + 1024 * j;
    const int row = gg >> 5, Lg = gg & 31;
    const int grow = r0 + row;
    if (grow < M) {
      const i32x4 v = *(const i32x4*)((const short*)ob + row * DD + ((Lg ^ (row & 7)) << 3));
      *(i32x4*)(OutB + (size_t)grow * DD + Lg * 8) = v;
    }
  }
}

// ---------------------------------------------------------------------------
// Node MLP (v14 verbatim): 512 thr; fused CSR aggregation in A-staging;
// ping-pong bf16 residual chain; f32 output on last layer only.
// ---------------------------------------------------------------------------
template<bool A_BF16, bool NODE>
__global__ __launch_bounds__(512, 4) void mlp_kernel(
    const void* __restrict__ Ain, const int* __restrict__ rowmap,
    const int* __restrict__ offs, const int* __restrict__ ssrc,
    const short* __restrict__ XbIn,
    const short* __restrict__ W1t, const short* __restrict__ W2t,
    const float* __restrict__ B1, const float* __restrict__ B2,
    const float* __restrict__ LG, const float* __restrict__ LB,
    short* __restrict__ OutB, float* __restrict__ OutF,
    short* __restrict__ XbOut, int M) {
  extern __shared__ char smem[];
  char* Abuf = smem + 32768;
  float* redbuf = (float*)(smem + 65536);
  const int tid = threadIdx.x;
  const int lane = tid & 63;
  const int wv = tid >> 6;
  const int wm = wv >> 2, wn = wv & 3;
  const int l15 = lane & 15, lq = lane >> 4;
  const int cbase = wn * 64;
  const int r0 = blockIdx.x * 64;

  auto stageW = [&](const short* Wt, int s, int slot) {
#pragma unroll
    for (int j = 0; j < 2; ++j) {
      const int c = tid + 512 * j;
      gld16(Wt + ((size_t)s * 1024 + c) * 8, smem + slot * 16384 + c * 16);
    }
  };

  stageW(W1t, 0, 0);

  if (NODE) {
    const short* efs = (const short*)Ain;
    const int r = tid & 63;
    const int j = tid >> 6;
    const int n = min(r0 + r, M - 1);
    const int beg = offs[n], end = offs[n + 1];
    float s[4][8];
#pragma unroll
    for (int c = 0; c < 4; ++c)
#pragma unroll
      for (int q = 0; q < 8; ++q) s[c][q] = 0.f;
    for (int p = beg; p < end; ++p) {
      const int src = ssrc[p];
#pragma unroll
      for (int c = 0; c < 4; ++c) {
        const int kq = j * 4 + c;
        const bf16x8 ev = *(const bf16x8*)(efs + (size_t)p * DD + kq * 8);
        const bf16x8 xv = *(const bf16x8*)(XbIn + (size_t)src * DD + kq * 8);
#pragma unroll
        for (int q = 0; q < 8; ++q) s[c][q] += bf2f(ev[q]) + bf2f(xv[q]);
      }
    }
#pragma unroll
    for (int c = 0; c < 4; ++c) {
      const int kq = j * 4 + c;
      bf16x8 o;
#pragma unroll
      for (int q = 0; q < 8; ++q) o[q] = f2bf(s[c][q]);
      *(bf16x8*)(Abuf + (kq * 64 + r) * 16) = o;
    }
  } else if (A_BF16) {
    const short* A = (const short*)Ain;
#pragma unroll
    for (int j = 0; j < 4; ++j) {
      const int c = tid + 512 * j;
      const int row = c & 63, kq = c >> 6;
      const int gr = min(r0 + row, M - 1);
      gld16(A + (size_t)gr * DD + kq * 8, Abuf + c * 16);
    }
  } else {
    const float* A = (const float*)Ain;
#pragma unroll
    for (int j = 0; j < 4; ++j) {
      const int c = tid + 512 * j;
      const int row = c & 63, kq = c >> 6;
      const int gr0 = min(r0 + row, M - 1);
      const int gr = rowmap ? rowmap[gr0] : gr0;
      const f32x4 u0 = *(const f32x4*)(A + (size_t)gr * DD + kq * 8);
      const f32x4 u1 = *(const f32x4*)(A + (size_t)gr * DD + kq * 8 + 4);
      bf16x8 o;
#pragma unroll
      for (int q = 0; q < 4; ++q) { o[q] = f2bf(u0[q]); o[q + 4] = f2bf(u1[q]); }
      *(bf16x8*)(Abuf + c * 16) = o;
    }
  }
  __syncthreads();

  f32x4 acc[2][4];
#pragma unroll
  for (int mi = 0; mi < 2; ++mi)
#pragma unroll
    for (int ni = 0; ni < 4; ++ni) acc[mi][ni] = (f32x4){0.f, 0.f, 0.f, 0.f};

#pragma unroll
  for (int s = 0; s < 8; ++s) {
    if (s < 7) stageW(W1t, s + 1, (s + 1) & 1);
    else       stageW(W2t, 0, 0);
    const char* wb = smem + (s & 1) * 16384;
    bf16x8 a[2], b[4];
#pragma unroll
    for (int mi = 0; mi < 2; ++mi)
      a[mi] = *(const bf16x8*)(Abuf + (((s * 4 + lq) * 64) + wm * 32 + mi * 16 + l15) * 16);
#pragma unroll
    for (int ni = 0; ni < 4; ++ni)
      b[ni] = *(const bf16x8*)(wb + lq * 4096 + (cbase + ni * 16 + l15) * 16);
#pragma unroll
    for (int ni = 0; ni < 4; ++ni)
#pragma unroll
      for (int mi = 0; mi < 2; ++mi)
        acc[mi][ni] = __builtin_amdgcn_mfma_f32_16x16x32_bf16(b[ni], a[mi], acc[mi][ni], 0, 0, 0);
    __syncthreads();
  }

  short* hid = (short*)Abuf;
  {
    f32x4 b1q[4];
#pragma unroll
    for (int ni = 0; ni < 4; ++ni)
      b1q[ni] = *(const f32x4*)(B1 + cbase + ni * 16 + lq * 4);
#pragma unroll
    for (int mi = 0; mi < 2; ++mi) {
      const int r = wm * 32 + mi * 16 + l15;
#pragma unroll
      for (int ni = 0; ni < 4; ++ni) {
        const int c4 = cbase + ni * 16 + lq * 4;
        s16x4 o;
#pragma unroll
        for (int i = 0; i < 4; ++i) {
          o[i] = f2bf(fmaxf(acc[mi][ni][i] + b1q[ni][i], 0.f));
          acc[mi][ni][i] = 0.f;
        }
        *(s16x4*)((char*)hid + r * 512 + (((c4 >> 3) ^ (r & 7)) << 4) + (c4 & 7) * 2) = o;
      }
    }
  }
  __syncthreads();

#pragma unroll
  for (int s = 0; s < 8; ++s) {
    if (s < 7) stageW(W2t, s + 1, (s + 1) & 1);
    const char* wb = smem + (s & 1) * 16384;
    bf16x8 a[2], b[4];
#pragma unroll
    for (int mi = 0; mi < 2; ++mi) {
      const int r = wm * 32 + mi * 16 + l15;
      a[mi] = *(const bf16x8*)((const char*)hid + r * 512 + ((((s * 4 + lq)) ^ (r & 7)) << 4));
    }
#pragma unroll
    for (int ni = 0; ni < 4; ++ni)
      b[ni] = *(const bf16x8*)(wb + lq * 4096 + (cbase + ni * 16 + l15) * 16);
#pragma unroll
    for (int ni = 0; ni < 4; ++ni)
#pragma unroll
      for (int mi = 0; mi < 2; ++mi)
        acc[mi][ni] = __builtin_amdgcn_mfma_f32_16x16x32_bf16(b[ni], a[mi], acc[mi][ni], 0, 0, 0);
    __syncthreads();
  }

  f32x4 b2q[4];
#pragma unroll
  for (int ni = 0; ni < 4; ++ni)
    b2q[ni] = *(const f32x4*)(B2 + cbase + ni * 16 + lq * 4);
  float mean_[2], inv_[2];
#pragma unroll
  for (int mi = 0; mi < 2; ++mi) {
    float s1 = 0.f, s2 = 0.f;
#pragma unroll
    for (int ni = 0; ni < 4; ++ni)
#pragma unroll
      for (int i = 0; i < 4; ++i) {
        const float v = acc[mi][ni][i] + b2q[ni][i];
        s1 += v; s2 += v * v;
      }
    s1 += __shfl_xor(s1, 16); s2 += __shfl_xor(s2, 16);
    s1 += __shfl_xor(s1, 32); s2 += __shfl_xor(s2, 32);
    mean_[mi] = s1; inv_[mi] = s2;
  }
  if (lq == 0) {
#pragma unroll
    for (int mi = 0; mi < 2; ++mi) {
      const int r = wm * 32 + mi * 16 + l15;
      redbuf[(r * 4 + wn) * 2 + 0] = mean_[mi];
      redbuf[(r * 4 + wn) * 2 + 1] = inv_[mi];
    }
  }
  __syncthreads();
#pragma unroll
  for (int mi = 0; mi < 2; ++mi) {
    const int r = wm * 32 + mi * 16 + l15;
    float t1 = 0.f, t2 = 0.f;
#pragma unroll
    for (int w = 0; w < 4; ++w) {
      t1 += redbuf[(r * 4 + w) * 2 + 0];
      t2 += redbuf[(r * 4 + w) * 2 + 1];
    }
    const float mean = t1 * (1.f / 256.f);
    const float var = t2 * (1.f / 256.f) - mean * mean;
    mean_[mi] = mean;
    inv_[mi] = rsqrtf(var + LN_EPS);
  }

  f32x4 gq[4], bq[4];
#pragma unroll
  for (int ni = 0; ni < 4; ++ni) {
    gq[ni] = *(const f32x4*)(LG + cbase + ni * 16 + lq * 4);
    bq[ni] = *(const f32x4*)(LB + cbase + ni * 16 + lq * 4);
  }

  if (NODE) {
    const bool wantF = (OutF != nullptr);
    if (!wantF) {
      short* ob = (short*)Abuf;
#pragma unroll
      for (int mi = 0; mi < 2; ++mi) {
        const int r = wm * 32 + mi * 16 + l15;
#pragma unroll
        for (int ni = 0; ni < 4; ++ni) {
          const int c4 = cbase + ni * 16 + lq * 4;
          s16x4 o;
#pragma unroll
          for (int i = 0; i < 4; ++i)
            o[i] = f2bf((acc[mi][ni][i] + b2q[ni][i] - mean_[mi]) * inv_[mi] * gq[ni][i] + bq[ni][i]);
          *(s16x4*)((char*)ob + r * 512 + (((c4 >> 3) ^ (r & 7)) << 4) + (c4 & 7) * 2) = o;
        }
      }
      __syncthreads();
#pragma unroll
      for (int j = 0; j < 4; ++j) {
        const int gg = tid + 512 * j;
        const int row = gg >> 5, Lg = gg & 31;
        const int grow = r0 + row;
        if (grow < M) {
          const i32x4 yv = *(const i32x4*)((const short*)ob + row * DD + ((Lg ^ (row & 7)) << 3));
          i32x4 xv = *(const i32x4*)(XbIn + (size_t)grow * DD + Lg * 8);
#pragma unroll
          for (int q = 0; q < 4; ++q) xv[q] = addbf2(yv[q], xv[q]);
          *(i32x4*)(XbOut + (size_t)grow * DD + Lg * 8) = xv;
        }
      }
    } else {
      float* ob = (float*)Abuf;
#pragma unroll
      for (int h = 0; h < 2; ++h) {
        if ((cbase >> 7) == h) {
#pragma unroll
          for (int mi = 0; mi < 2; ++mi) {
            const int r = wm * 32 + mi * 16 + l15;
#pragma unroll
            for (int ni = 0; ni < 4; ++ni) {
              const int cl4 = cbase - h * 128 + ni * 16 + lq * 4;
              f32x4 y;
#pragma unroll
              for (int i = 0; i < 4; ++i)
                y[i] = (acc[mi][ni][i] + b2q[ni][i] - mean_[mi]) * inv_[mi] * gq[ni][i] + bq[ni][i];
              *(f32x4*)((char*)ob + r * 512 + ((((cl4 >> 2) ^ (r & 7))) << 4)) = y;
            }
          }
        }
        __syncthreads();
#pragma unroll
        for (int j = 0; j < 4; ++j) {
          const int gg = tid + 512 * j;
          const int row = gg >> 5, Lc = gg & 31;
          const int grow = r0 + row;
          if (grow < M) {
            f32x4 v = *(const f32x4*)(ob + row * 128 + ((Lc ^ (row & 7)) << 2));
            const s16x4 xr = *(const s16x4*)(XbIn + (size_t)grow * DD + h * 128 + Lc * 4);
            v.x += bf2f(xr.x); v.y += bf2f(xr.y); v.z += bf2f(xr.z); v.w += bf2f(xr.w);
            *(f32x4*)(OutF + (size_t)grow * DD + h * 128 + Lc * 4) = v;
          }
        }
        if (h == 0) __syncthreads();
      }
    }
  } else {
    short* ob = (short*)Abuf;
#pragma unroll
    for (int mi = 0; mi < 2; ++mi) {
      const int r = wm * 32 + mi * 16 + l15;
#pragma unroll
      for (int ni = 0; ni < 4; ++ni) {
        const int c4 = cbase + ni * 16 + lq * 4;
        s16x4 o;
#pragma unroll
        for (int i = 0; i < 4; ++i)
          o[i] = f2bf((acc[mi][ni][i] + b2q[ni][i] - mean_[mi]) * inv_[mi] * gq[ni][i] + bq[ni][i]);
        *(s16x4*)((char*)ob + r * 512 + (((c4 >> 3) ^ (r & 7)) << 4) + (c4 & 7) * 2) = o;
      }
    }
    __syncthreads();
#pragma unroll
    for (int j = 0; j < 4; ++j) {
      const int gg = tid + 512 * j;
      const int row = gg >> 5, Lg = gg & 31;
      const int grow = r0 + row;
      if (grow < M) {
        const i32x4 v = *(const i32x4*)((const short*)ob + row * DD + ((Lg ^ (row & 7)) << 3));
        *(i32x4*)(OutB + (size_t)grow * DD + Lg * 8) = v;
      }
    }
  }
}

__global__ void count_kernel(const int* __restrict__ tgt, int* __restrict__ deg) {
  const int e = blockIdx.x * 256 + threadIdx.x;
  if (e < NEDGE) atomicAdd(&deg[tgt[e]], 1);
}

// ---------- 3-stage multi-block exclusive scan ----------
__global__ __launch_bounds__(256) void scan1_kernel(
    const int* __restrict__ deg, int* __restrict__ locex, int* __restrict__ bsum) {
  __shared__ int sh[256];
  const int t = threadIdx.x, b = blockIdx.x;
  const int idx = b * 256 + t;
  const int v = (idx < NNODE) ? deg[idx] : 0;
  sh[t] = v;
  __syncthreads();
#pragma unroll
  for (int off = 1; off < 256; off <<= 1) {
    const int add = (t >= off) ? sh[t - off] : 0;
    __syncthreads();
    sh[t] += add;
    __syncthreads();
  }
  if (idx < NNODE) locex[idx] = sh[t] - v;
  if (t == 255) bsum[b] = sh[255];
}

__global__ __launch_bounds__(512) void scan2_kernel(int* __restrict__ bsum, int nb) {
  __shared__ int sh[512];
  const int t = threadIdx.x;
  const int v = (t < nb) ? bsum[t] : 0;
  sh[t] = v;
  __syncthreads();
#pragma unroll
  for (int off = 1; off < 512; off <<= 1) {
    const int add = (t >= off) ? sh[t - off] : 0;
    __syncthreads();
    sh[t] += add;
    __syncthreads();
  }
  if (t < nb) bsum[t] = sh[t] - v;
}

__global__ __launch_bounds__(256) void scan3_kernel(
    const int* __restrict__ locex, const int* __restrict__ bsum,
    int* __restrict__ offs, int* __restrict__ cur) {
  const int idx = blockIdx.x * 256 + threadIdx.x;
  if (idx < NNODE) {
    const int o = locex[idx] + bsum[blockIdx.x];
    offs[idx] = o;
    cur[idx] = o;
  }
  if (idx == 0) offs[NNODE] = NEDGE;
}

__global__ void fill_kernel(const int* __restrict__ src, const int* __restrict__ tgt,
                            int* cur, int* seid, int* ssrc) {
  const int e = blockIdx.x * 256 + threadIdx.x;
  if (e < NEDGE) {
    const int t = tgt[e];
    const int p = atomicAdd(&cur[t], 1);
    seid[p] = e;
    ssrc[p] = src[e];
  }
}

__global__ void cvt4_kernel(const float* __restrict__ src, short* __restrict__ dst, int n4) {
  for (int i = blockIdx.x * blockDim.x + threadIdx.x; i < n4; i += gridDim.x * blockDim.x) {
    const f32x4 v = ((const f32x4*)src)[i];
    s16x4 o;
    o.x = f2bf(v.x); o.y = f2bf(v.y); o.z = f2bf(v.z); o.w = f2bf(v.w);
    ((s16x4*)dst)[i] = o;
  }
}

__global__ __launch_bounds__(256) void gather_cvt_kernel(
    const float* __restrict__ src, const int* __restrict__ perm,
    short* __restrict__ dst, int n) {
  const int w = (blockIdx.x * blockDim.x + threadIdx.x) >> 6;
  if (w >= n) return;
  const int lane = threadIdx.x & 63;
  const f32x4 v = *(const f32x4*)(src + (size_t)perm[w] * DD + lane * 4);
  s16x4 o; o.x = f2bf(v.x); o.y = f2bf(v.y); o.z = f2bf(v.z); o.w = f2bf(v.w);
  *(s16x4*)(dst + (size_t)w * DD + lane * 4) = o;
}

// ---------------------------------------------------------------------------
extern "C" void kernel_launch(void* const* d_in, const int* in_sizes, int n_in,
                              void* d_out, int out_size, void* d_ws, size_t ws_size,
                              hipStream_t stream) {
  const float* x_in = (const float*)d_in[0];
  const float* ea_f = (const float*)d_in[1];
  const float* e1w = (const float*)d_in[2];
  const float* e1b = (const float*)d_in[3];
  const float* e2w = (const float*)d_in[4];
  const float* e2b = (const float*)d_in[5];
  const float* elg = (const float*)d_in[6];
  const float* elb = (const float*)d_in[7];
  const float* n1w = (const float*)d_in[8];
  const float* n1b = (const float*)d_in[9];
  const float* n2w = (const float*)d_in[10];
  const float* n2b = (const float*)d_in[11];
  const float* nlg = (const float*)d_in[12];
  const float* nlb = (const float*)d_in[13];
  const int* eidx = (const int*)d_in[14];
  float* x = (float*)d_out;

  char* p = (char*)d_ws;
  auto take = [&](size_t bytes) {
    char* r = p;
    p += (bytes + 255) & ~(size_t)255;
    return r;
  };
  short* efeat = (short*)take((size_t)NEDGE * DD * 2);
  short* xbA = (short*)take((size_t)NNODE * DD * 2);
  short* xbB = (short*)take((size_t)NNODE * DD * 2);
  short* we1t = (short*)take((size_t)NLAY * DD * DD * 2);
  short* we2t = (short*)take((size_t)NLAY * DD * DD * 2);
  short* wn1t = (short*)take((size_t)NLAY * DD * DD * 2);
  short* wn2t = (short*)take((size_t)NLAY * DD * DD * 2);
  int* deg = (int*)take((size_t)NNODE * 4);
  int* offs = (int*)take((size_t)(NNODE + 1) * 4);
  int* cur = (int*)take((size_t)NNODE * 4);
  int* seid = (int*)take((size_t)NEDGE * 4);
  int* ssrc = (int*)take((size_t)NEDGE * 4);
  int* locex = (int*)take((size_t)(NNODE + 256) * 4);
  int* bsum = (int*)take(512 * 4);
  short* eab = (short*)take((size_t)NEDGE * DD * 2);
  const bool use_eab = ((size_t)(p - (char*)d_ws) <= ws_size);

  const int SMEM_E = 69632;
  const int SMEM_N = 67584;
  hipFuncSetAttribute((const void*)edge_kernel<true>,
                      hipFuncAttributeMaxDynamicSharedMemorySize, SMEM_E);
  hipFuncSetAttribute((const void*)edge_kernel<false>,
                      hipFuncAttributeMaxDynamicSharedMemorySize, SMEM_E);
  hipFuncSetAttribute((const void*)mlp_kernel<true, true>,
                      hipFuncAttributeMaxDynamicSharedMemorySize, SMEM_N);

  cvtw_kernel<<<288, 256, 0, stream>>>(e1w, we1t, NLAY);
  cvtw_kernel<<<288, 256, 0, stream>>>(e2w, we2t, NLAY);
  cvtw_kernel<<<288, 256, 0, stream>>>(n1w, wn1t, NLAY);
  cvtw_kernel<<<288, 256, 0, stream>>>(n2w, wn2t, NLAY);
  cvt4_kernel<<<2048, 256, 0, stream>>>(x_in, xbA, NNODE * DD / 4);

  const int NB = (NNODE + 255) / 256;  // 391
  hipMemsetAsync(deg, 0, (size_t)NNODE * 4, stream);
  count_kernel<<<(NEDGE + 255) / 256, 256, 0, stream>>>(eidx + NEDGE, deg);
  scan1_kernel<<<NB, 256, 0, stream>>>(deg, locex, bsum);
  scan2_kernel<<<1, 512, 0, stream>>>(bsum, NB);
  scan3_kernel<<<NB, 256, 0, stream>>>(locex, bsum, offs, cur);
  fill_kernel<<<(NEDGE + 255) / 256, 256, 0, stream>>>(eidx, eidx + NEDGE, cur, seid, ssrc);
  if (use_eab)
    gather_cvt_kernel<<<NEDGE / 4, 256, 0, stream>>>(ea_f, seid, eab, NEDGE);

  const int egrid = (NEDGE + 63) / 64;
  const int ngrid = (NNODE + 63) / 64;
  short* xin = xbA;
  short* xout = xbB;
  for (int l = 0; l < NLAY; ++l) {
    if (use_eab) {
      edge_kernel<true><<<egrid, 1024, SMEM_E, stream>>>(
          eab, nullptr, we1t + l * 65536, we2t + l * 65536, e1b + l * DD,
          e2b + l * DD, elg + l * DD, elb + l * DD, efeat, NEDGE);
    } else {
      edge_kernel<false><<<egrid, 1024, SMEM_E, stream>>>(
          ea_f, seid, we1t + l * 65536, we2t + l * 65536, e1b + l * DD,
          e2b + l * DD, elg + l * DD, elb + l * DD, efeat, NEDGE);
    }
    mlp_kernel<true, true><<<ngrid, 512, SMEM_N, stream>>>(
        efeat, nullptr, offs, ssrc, xin,
        wn1t + l * 65536, wn2t + l * 65536, n1b + l * DD,
        n2b + l * DD, nlg + l * DD, nlb + l * DD, nullptr,
        (l == NLAY - 1) ? x : nullptr, xout, NNODE);
    short* t = xin; xin = xout; xout = t;
  }
  (void)in_sizes; (void)n_in; (void)out_size; (void)ws_size;
}

// Round 17
// 2576.006 us; speedup vs baseline: 1.1927x; 1.1927x over previous
//
#include <hip/hip_runtime.h>
#include <stdint.h>

#define DD 256
#define NEDGE 300000
#define NNODE 100000
#define NLAY 9
#define LN_EPS 1e-5f

typedef __attribute__((ext_vector_type(8))) short bf16x8;
typedef __attribute__((ext_vector_type(4))) short s16x4;
typedef __attribute__((ext_vector_type(4))) float f32x4;
typedef __attribute__((ext_vector_type(4))) int i32x4;

static __device__ __forceinline__ short f2bf(float f) {
  union { float f; uint32_t u; } v; v.f = f;
  uint32_t r = (v.u + 0x7FFFu + ((v.u >> 16) & 1u)) >> 16;
  return (short)(uint16_t)r;
}
static __device__ __forceinline__ float bf2f(short s) {
  union { uint32_t u; float f; } v; v.u = ((uint32_t)(uint16_t)s) << 16;
  return v.f;
}
// packed bf16 pair add: r = bf16(a.lo+b.lo) | bf16(a.hi+b.hi)<<16
static __device__ __forceinline__ int addbf2(int a, int b) {
  const float a0 = bf2f((short)(a & 0xffff)), a1 = bf2f((short)(((uint32_t)a) >> 16));
  const float b0 = bf2f((short)(b & 0xffff)), b1 = bf2f((short)(((uint32_t)b) >> 16));
  const uint16_t r0 = (uint16_t)f2bf(a0 + b0), r1 = (uint16_t)f2bf(a1 + b1);
  return (int)(((uint32_t)r1 << 16) | r0);
}

static __device__ __forceinline__ void gld16(const void* g, void* l) {
  __builtin_amdgcn_global_load_lds((const __attribute__((address_space(1))) void*)g,
                                   (__attribute__((address_space(3))) void*)l, 16, 0, 0);
}

// ---------------------------------------------------------------------------
// Weight pre-transpose + bf16 for all 4 weight groups in ONE launch.
// Per group: chunk j (16B) = kq*256+col holds W[col][kq*8..kq*8+7];
// K-slice s = chunks [s*1024, (s+1)*1024).
// ---------------------------------------------------------------------------
__global__ void cvtw4_kernel(const float* __restrict__ s0, const float* __restrict__ s1,
                             const float* __restrict__ s2, const float* __restrict__ s3,
                             short* __restrict__ d0, short* __restrict__ d1,
                             short* __restrict__ d2, short* __restrict__ d3) {
  const int per = NLAY * 8192;  // 73728 chunks per group
  const int total = 4 * per;
  for (int j = blockIdx.x * blockDim.x + threadIdx.x; j < total; j += gridDim.x * blockDim.x) {
    const int grp = j / per;
    const int jj = j - grp * per;
    const float* src = (grp == 0) ? s0 : (grp == 1) ? s1 : (grp == 2) ? s2 : s3;
    short* dst = (grp == 0) ? d0 : (grp == 1) ? d1 : (grp == 2) ? d2 : d3;
    const int m = jj >> 13;
    const int r = jj & 8191;
    const int col = r & 255;
    const int kq = r >> 8;
    const float* s = src + (size_t)m * 65536 + col * 256 + kq * 8;
    const f32x4 u0 = *(const f32x4*)(s);
    const f32x4 u1 = *(const f32x4*)(s + 4);
    bf16x8 o;
#pragma unroll
    for (int q = 0; q < 4; ++q) { o[q] = f2bf(u0[q]); o[q + 4] = f2bf(u1[q]); }
    *(bf16x8*)(dst + (size_t)(m * 8192 + r) * 8) = o;
  }
}

// ---------------------------------------------------------------------------
// Fused MLP v17 (= v14): 512 thr = 8 waves (2M x 4N); tile 64r x 256c; wave
// 32r x 64c; acc[2][4]. Swapped-operand MFMA (lane=row, regs=4 cols).
// NODE: fused CSR aggregation in A-staging; ping-pong bf16 residual chain
// (reads XbIn, writes XbOut); f32 OutF written only on last layer.
// LDS: Wslot0 @0, Wslot1 @16384, A/hidden @32768 (32KB), red @65536 (2KB).
// ---------------------------------------------------------------------------
template<bool A_BF16, bool NODE>
__global__ __launch_bounds__(512, 4) void mlp_kernel(
    const void* __restrict__ Ain, const int* __restrict__ rowmap,
    const int* __restrict__ offs, const int* __restrict__ ssrc,
    const short* __restrict__ XbIn,
    const short* __restrict__ W1t, const short* __restrict__ W2t,
    const float* __restrict__ B1, const float* __restrict__ B2,
    const float* __restrict__ LG, const float* __restrict__ LB,
    short* __restrict__ OutB, float* __restrict__ OutF,
    short* __restrict__ XbOut, int M) {
  extern __shared__ char smem[];
  char* Abuf = smem + 32768;
  float* redbuf = (float*)(smem + 65536);
  const int tid = threadIdx.x;
  const int lane = tid & 63;
  const int wv = tid >> 6;
  const int wm = wv >> 2, wn = wv & 3;
  const int l15 = lane & 15, lq = lane >> 4;
  const int cbase = wn * 64;
  const int r0 = blockIdx.x * 64;

  auto stageW = [&](const short* Wt, int s, int slot) {
#pragma unroll
    for (int j = 0; j < 2; ++j) {
      const int c = tid + 512 * j;
      gld16(Wt + ((size_t)s * 1024 + c) * 8, smem + slot * 16384 + c * 16);
    }
  };

  stageW(W1t, 0, 0);  // issue W DMA first so it overlaps the A stage below

  // ---- stage A tile: [kq][row][16B], conflict-free ----
  if (NODE) {
    // fused aggregation: lane r = node, wave j = kq slice (4 chunks)
    const short* efs = (const short*)Ain;
    const int r = tid & 63;
    const int j = tid >> 6;
    const int n = min(r0 + r, M - 1);
    const int beg = offs[n], end = offs[n + 1];
    float s[4][8];
#pragma unroll
    for (int c = 0; c < 4; ++c)
#pragma unroll
      for (int q = 0; q < 8; ++q) s[c][q] = 0.f;
    for (int p = beg; p < end; ++p) {
      const int src = ssrc[p];
#pragma unroll
      for (int c = 0; c < 4; ++c) {
        const int kq = j * 4 + c;
        const bf16x8 ev = *(const bf16x8*)(efs + (size_t)p * DD + kq * 8);
        const bf16x8 xv = *(const bf16x8*)(XbIn + (size_t)src * DD + kq * 8);
#pragma unroll
        for (int q = 0; q < 8; ++q) s[c][q] += bf2f(ev[q]) + bf2f(xv[q]);
      }
    }
#pragma unroll
    for (int c = 0; c < 4; ++c) {
      const int kq = j * 4 + c;
      bf16x8 o;
#pragma unroll
      for (int q = 0; q < 8; ++q) o[q] = f2bf(s[c][q]);
      *(bf16x8*)(Abuf + (kq * 64 + r) * 16) = o;
    }
  } else if (A_BF16) {
    const short* A = (const short*)Ain;
#pragma unroll
    for (int j = 0; j < 4; ++j) {
      const int c = tid + 512 * j;
      const int row = c & 63, kq = c >> 6;
      const int gr = min(r0 + row, M - 1);
      gld16(A + (size_t)gr * DD + kq * 8, Abuf + c * 16);
    }
  } else {
    const float* A = (const float*)Ain;
#pragma unroll
    for (int j = 0; j < 4; ++j) {
      const int c = tid + 512 * j;
      const int row = c & 63, kq = c >> 6;
      const int gr0 = min(r0 + row, M - 1);
      const int gr = rowmap ? rowmap[gr0] : gr0;
      const f32x4 u0 = *(const f32x4*)(A + (size_t)gr * DD + kq * 8);
      const f32x4 u1 = *(const f32x4*)(A + (size_t)gr * DD + kq * 8 + 4);
      bf16x8 o;
#pragma unroll
      for (int q = 0; q < 4; ++q) { o[q] = f2bf(u0[q]); o[q + 4] = f2bf(u1[q]); }
      *(bf16x8*)(Abuf + c * 16) = o;
    }
  }
  __syncthreads();  // A + W1 slice0 ready

  f32x4 acc[2][4];
#pragma unroll
  for (int mi = 0; mi < 2; ++mi)
#pragma unroll
    for (int ni = 0; ni < 4; ++ni) acc[mi][ni] = (f32x4){0.f, 0.f, 0.f, 0.f};

  // ---------------- GEMM1: h^T = (A @ W1^T)^T via mfma(W, A, acc) ----------
#pragma unroll
  for (int s = 0; s < 8; ++s) {
    if (s < 7) stageW(W1t, s + 1, (s + 1) & 1);
    else       stageW(W2t, 0, 0);
    const char* wb = smem + (s & 1) * 16384;
    bf16x8 a[2], b[4];
#pragma unroll
    for (int mi = 0; mi < 2; ++mi)
      a[mi] = *(const bf16x8*)(Abuf + (((s * 4 + lq) * 64) + wm * 32 + mi * 16 + l15) * 16);
#pragma unroll
    for (int ni = 0; ni < 4; ++ni)
      b[ni] = *(const bf16x8*)(wb + lq * 4096 + (cbase + ni * 16 + l15) * 16);
#pragma unroll
    for (int ni = 0; ni < 4; ++ni)
#pragma unroll
      for (int mi = 0; mi < 2; ++mi)
        acc[mi][ni] = __builtin_amdgcn_mfma_f32_16x16x32_bf16(b[ni], a[mi], acc[mi][ni], 0, 0, 0);
    __syncthreads();
  }

  // ---- EPI1: bias+relu -> hidden; thread holds 4 consecutive cols --------
  short* hid = (short*)Abuf;
  {
    f32x4 b1q[4];
#pragma unroll
    for (int ni = 0; ni < 4; ++ni)
      b1q[ni] = *(const f32x4*)(B1 + cbase + ni * 16 + lq * 4);
#pragma unroll
    for (int mi = 0; mi < 2; ++mi) {
      const int r = wm * 32 + mi * 16 + l15;
#pragma unroll
      for (int ni = 0; ni < 4; ++ni) {
        const int c4 = cbase + ni * 16 + lq * 4;
        s16x4 o;
#pragma unroll
        for (int i = 0; i < 4; ++i) {
          o[i] = f2bf(fmaxf(acc[mi][ni][i] + b1q[ni][i], 0.f));
          acc[mi][ni][i] = 0.f;
        }
        *(s16x4*)((char*)hid + r * 512 + (((c4 >> 3) ^ (r & 7)) << 4) + (c4 & 7) * 2) = o;
      }
    }
  }
  __syncthreads();  // hidden ready

  // ---------------- GEMM2: y^T = (h @ W2^T)^T ------------------------------
#pragma unroll
  for (int s = 0; s < 8; ++s) {
    if (s < 7) stageW(W2t, s + 1, (s + 1) & 1);
    const char* wb = smem + (s & 1) * 16384;
    bf16x8 a[2], b[4];
#pragma unroll
    for (int mi = 0; mi < 2; ++mi) {
      const int r = wm * 32 + mi * 16 + l15;
      a[mi] = *(const bf16x8*)((const char*)hid + r * 512 + ((((s * 4 + lq)) ^ (r & 7)) << 4));
    }
#pragma unroll
    for (int ni = 0; ni < 4; ++ni)
      b[ni] = *(const bf16x8*)(wb + lq * 4096 + (cbase + ni * 16 + l15) * 16);
#pragma unroll
    for (int ni = 0; ni < 4; ++ni)
#pragma unroll
      for (int mi = 0; mi < 2; ++mi)
        acc[mi][ni] = __builtin_amdgcn_mfma_f32_16x16x32_bf16(b[ni], a[mi], acc[mi][ni], 0, 0, 0);
    __syncthreads();
  }

  // ---------------- LN: per-row over regs + 2 shuffle stages ---------------
  f32x4 b2q[4];
#pragma unroll
  for (int ni = 0; ni < 4; ++ni)
    b2q[ni] = *(const f32x4*)(B2 + cbase + ni * 16 + lq * 4);
  float mean_[2], inv_[2];
#pragma unroll
  for (int mi = 0; mi < 2; ++mi) {
    float s1 = 0.f, s2 = 0.f;
#pragma unroll
    for (int ni = 0; ni < 4; ++ni)
#pragma unroll
      for (int i = 0; i < 4; ++i) {
        const float v = acc[mi][ni][i] + b2q[ni][i];
        s1 += v; s2 += v * v;
      }
    s1 += __shfl_xor(s1, 16); s2 += __shfl_xor(s2, 16);
    s1 += __shfl_xor(s1, 32); s2 += __shfl_xor(s2, 32);
    mean_[mi] = s1; inv_[mi] = s2;
  }
  if (lq == 0) {
#pragma unroll
    for (int mi = 0; mi < 2; ++mi) {
      const int r = wm * 32 + mi * 16 + l15;
      redbuf[(r * 4 + wn) * 2 + 0] = mean_[mi];
      redbuf[(r * 4 + wn) * 2 + 1] = inv_[mi];
    }
  }
  __syncthreads();  // redbuf ready
#pragma unroll
  for (int mi = 0; mi < 2; ++mi) {
    const int r = wm * 32 + mi * 16 + l15;
    float t1 = 0.f, t2 = 0.f;
#pragma unroll
    for (int w = 0; w < 4; ++w) {
      t1 += redbuf[(r * 4 + w) * 2 + 0];
      t2 += redbuf[(r * 4 + w) * 2 + 1];
    }
    const float mean = t1 * (1.f / 256.f);
    const float var = t2 * (1.f / 256.f) - mean * mean;
    mean_[mi] = mean;
    inv_[mi] = rsqrtf(var + LN_EPS);
  }

  f32x4 gq[4], bq[4];
#pragma unroll
  for (int ni = 0; ni < 4; ++ni) {
    gq[ni] = *(const f32x4*)(LG + cbase + ni * 16 + lq * 4);
    bq[ni] = *(const f32x4*)(LB + cbase + ni * 16 + lq * 4);
  }

  if (NODE) {
    const bool wantF = (OutF != nullptr);
    if (!wantF) {
      // layers 0..L-2: y + xbIn -> XbOut (bf16)
      short* ob = (short*)Abuf;
#pragma unroll
      for (int mi = 0; mi < 2; ++mi) {
        const int r = wm * 32 + mi * 16 + l15;
#pragma unroll
        for (int ni = 0; ni < 4; ++ni) {
          const int c4 = cbase + ni * 16 + lq * 4;
          s16x4 o;
#pragma unroll
          for (int i = 0; i < 4; ++i)
            o[i] = f2bf((acc[mi][ni][i] + b2q[ni][i] - mean_[mi]) * inv_[mi] * gq[ni][i] + bq[ni][i]);
          *(s16x4*)((char*)ob + r * 512 + (((c4 >> 3) ^ (r & 7)) << 4) + (c4 & 7) * 2) = o;
        }
      }
      __syncthreads();  // ob ready
#pragma unroll
      for (int j = 0; j < 4; ++j) {
        const int gg = tid + 512 * j;
        const int row = gg >> 5, Lg = gg & 31;
        const int grow = r0 + row;
        if (grow < M) {
          const i32x4 yv = *(const i32x4*)((const short*)ob + row * DD + ((Lg ^ (row & 7)) << 3));
          i32x4 xv = *(const i32x4*)(XbIn + (size_t)grow * DD + Lg * 8);
#pragma unroll
          for (int q = 0; q < 4; ++q) xv[q] = addbf2(yv[q], xv[q]);
          *(i32x4*)(XbOut + (size_t)grow * DD + Lg * 8) = xv;
        }
      }
    } else {
      // last layer: f32 two-pass output (full precision add vs bf16 xbIn)
      float* ob = (float*)Abuf;
#pragma unroll
      for (int h = 0; h < 2; ++h) {
        if ((cbase >> 7) == h) {
#pragma unroll
          for (int mi = 0; mi < 2; ++mi) {
            const int r = wm * 32 + mi * 16 + l15;
#pragma unroll
            for (int ni = 0; ni < 4; ++ni) {
              const int cl4 = cbase - h * 128 + ni * 16 + lq * 4;
              f32x4 y;
#pragma unroll
              for (int i = 0; i < 4; ++i)
                y[i] = (acc[mi][ni][i] + b2q[ni][i] - mean_[mi]) * inv_[mi] * gq[ni][i] + bq[ni][i];
              *(f32x4*)((char*)ob + r * 512 + ((((cl4 >> 2) ^ (r & 7))) << 4)) = y;
            }
          }
        }
        __syncthreads();  // ob(h) ready
#pragma unroll
        for (int j = 0; j < 4; ++j) {
          const int gg = tid + 512 * j;
          const int row = gg >> 5, Lc = gg & 31;
          const int grow = r0 + row;
          if (grow < M) {
            f32x4 v = *(const f32x4*)(ob + row * 128 + ((Lc ^ (row & 7)) << 2));
            const s16x4 xr = *(const s16x4*)(XbIn + (size_t)grow * DD + h * 128 + Lc * 4);
            v.x += bf2f(xr.x); v.y += bf2f(xr.y); v.z += bf2f(xr.z); v.w += bf2f(xr.w);
            *(f32x4*)(OutF + (size_t)grow * DD + h * 128 + Lc * 4) = v;
          }
        }
        if (h == 0) __syncthreads();
      }
    }
  } else {
    short* ob = (short*)Abuf;  // 64 x 256 bf16, 16B-granule swizzle
#pragma unroll
    for (int mi = 0; mi < 2; ++mi) {
      const int r = wm * 32 + mi * 16 + l15;
#pragma unroll
      for (int ni = 0; ni < 4; ++ni) {
        const int c4 = cbase + ni * 16 + lq * 4;
        s16x4 o;
#pragma unroll
        for (int i = 0; i < 4; ++i)
          o[i] = f2bf((acc[mi][ni][i] + b2q[ni][i] - mean_[mi]) * inv_[mi] * gq[ni][i] + bq[ni][i]);
        *(s16x4*)((char*)ob + r * 512 + (((c4 >> 3) ^ (r & 7)) << 4) + (c4 & 7) * 2) = o;
      }
    }
    __syncthreads();  // ob ready
#pragma unroll
    for (int j = 0; j < 4; ++j) {
      const int gg = tid + 512 * j;
      const int row = gg >> 5, Lg = gg & 31;
      const int grow = r0 + row;
      if (grow < M) {
        const i32x4 v = *(const i32x4*)((const short*)ob + row * DD + ((Lg ^ (row & 7)) << 3));
        *(i32x4*)(OutB + (size_t)grow * DD + Lg * 8) = v;
      }
    }
  }
}

__global__ void count_kernel(const int* __restrict__ tgt, int* __restrict__ deg) {
  const int e = blockIdx.x * 256 + threadIdx.x;
  if (e < NEDGE) atomicAdd(&deg[tgt[e]], 1);
}

// ---------- 3-stage multi-block exclusive scan ----------
__global__ __launch_bounds__(256) void scan1_kernel(
    const int* __restrict__ deg, int* __restrict__ locex, int* __restrict__ bsum) {
  __shared__ int sh[256];
  const int t = threadIdx.x, b = blockIdx.x;
  const int idx = b * 256 + t;
  const int v = (idx < NNODE) ? deg[idx] : 0;
  sh[t] = v;
  __syncthreads();
#pragma unroll
  for (int off = 1; off < 256; off <<= 1) {
    const int add = (t >= off) ? sh[t - off] : 0;
    __syncthreads();
    sh[t] += add;
    __syncthreads();
  }
  if (idx < NNODE) locex[idx] = sh[t] - v;
  if (t == 255) bsum[b] = sh[255];
}

__global__ __launch_bounds__(512) void scan2_kernel(int* __restrict__ bsum, int nb) {
  __shared__ int sh[512];
  const int t = threadIdx.x;
  const int v = (t < nb) ? bsum[t] : 0;
  sh[t] = v;
  __syncthreads();
#pragma unroll
  for (int off = 1; off < 512; off <<= 1) {
    const int add = (t >= off) ? sh[t - off] : 0;
    __syncthreads();
    sh[t] += add;
    __syncthreads();
  }
  if (t < nb) bsum[t] = sh[t] - v;
}

__global__ __launch_bounds__(256) void scan3_kernel(
    const int* __restrict__ locex, const int* __restrict__ bsum,
    int* __restrict__ offs, int* __restrict__ cur) {
  const int idx = blockIdx.x * 256 + threadIdx.x;
  if (idx < NNODE) {
    const int o = locex[idx] + bsum[blockIdx.x];
    offs[idx] = o;
    cur[idx] = o;
  }
  if (idx == 0) offs[NNODE] = NEDGE;
}

__global__ void fill_kernel(const int* __restrict__ src, const int* __restrict__ tgt,
                            int* cur, int* seid, int* ssrc) {
  const int e = blockIdx.x * 256 + threadIdx.x;
  if (e < NEDGE) {
    const int t = tgt[e];
    const int p = atomicAdd(&cur[t], 1);
    seid[p] = e;
    ssrc[p] = src[e];
  }
}

__global__ void cvt4_kernel(const float* __restrict__ src, short* __restrict__ dst, int n4) {
  for (int i = blockIdx.x * blockDim.x + threadIdx.x; i < n4; i += gridDim.x * blockDim.x) {
    const f32x4 v = ((const f32x4*)src)[i];
    s16x4 o;
    o.x = f2bf(v.x); o.y = f2bf(v.y); o.z = f2bf(v.z); o.w = f2bf(v.w);
    ((s16x4*)dst)[i] = o;
  }
}

__global__ __launch_bounds__(256) void gather_cvt_kernel(
    const float* __restrict__ src, const int* __restrict__ perm,
    short* __restrict__ dst, int n) {
  const int w = (blockIdx.x * blockDim.x + threadIdx.x) >> 6;
  if (w >= n) return;
  const int lane = threadIdx.x & 63;
  const f32x4 v = *(const f32x4*)(src + (size_t)perm[w] * DD + lane * 4);
  s16x4 o; o.x = f2bf(v.x); o.y = f2bf(v.y); o.z = f2bf(v.z); o.w = f2bf(v.w);
  *(s16x4*)(dst + (size_t)w * DD + lane * 4) = o;
}

// ---------------------------------------------------------------------------
extern "C" void kernel_launch(void* const* d_in, const int* in_sizes, int n_in,
                              void* d_out, int out_size, void* d_ws, size_t ws_size,
                              hipStream_t stream) {
  const float* x_in = (const float*)d_in[0];
  const float* ea_f = (const float*)d_in[1];
  const float* e1w = (const float*)d_in[2];
  const float* e1b = (const float*)d_in[3];
  const float* e2w = (const float*)d_in[4];
  const float* e2b = (const float*)d_in[5];
  const float* elg = (const float*)d_in[6];
  const float* elb = (const float*)d_in[7];
  const float* n1w = (const float*)d_in[8];
  const float* n1b = (const float*)d_in[9];
  const float* n2w = (const float*)d_in[10];
  const float* n2b = (const float*)d_in[11];
  const float* nlg = (const float*)d_in[12];
  const float* nlb = (const float*)d_in[13];
  const int* eidx = (const int*)d_in[14];
  float* x = (float*)d_out;

  char* p = (char*)d_ws;
  auto take = [&](size_t bytes) {
    char* r = p;
    p += (bytes + 255) & ~(size_t)255;
    return r;
  };
  short* efeat = (short*)take((size_t)NEDGE * DD * 2);
  short* xbA = (short*)take((size_t)NNODE * DD * 2);
  short* xbB = (short*)take((size_t)NNODE * DD * 2);
  short* we1t = (short*)take((size_t)NLAY * DD * DD * 2);
  short* we2t = (short*)take((size_t)NLAY * DD * DD * 2);
  short* wn1t = (short*)take((size_t)NLAY * DD * DD * 2);
  short* wn2t = (short*)take((size_t)NLAY * DD * DD * 2);
  int* deg = (int*)take((size_t)NNODE * 4);
  int* offs = (int*)take((size_t)(NNODE + 1) * 4);
  int* cur = (int*)take((size_t)NNODE * 4);
  int* seid = (int*)take((size_t)NEDGE * 4);
  int* ssrc = (int*)take((size_t)NEDGE * 4);
  int* locex = (int*)take((size_t)(NNODE + 256) * 4);
  int* bsum = (int*)take(512 * 4);
  short* eab = (short*)take((size_t)NEDGE * DD * 2);
  const bool use_eab = ((size_t)(p - (char*)d_ws) <= ws_size);

  const int SMEM = 67584;
  hipFuncSetAttribute((const void*)mlp_kernel<true, false>,
                      hipFuncAttributeMaxDynamicSharedMemorySize, SMEM);
  hipFuncSetAttribute((const void*)mlp_kernel<false, false>,
                      hipFuncAttributeMaxDynamicSharedMemorySize, SMEM);
  hipFuncSetAttribute((const void*)mlp_kernel<true, true>,
                      hipFuncAttributeMaxDynamicSharedMemorySize, SMEM);

  cvtw4_kernel<<<1152, 256, 0, stream>>>(e1w, e2w, n1w, n2w, we1t, we2t, wn1t, wn2t);
  cvt4_kernel<<<2048, 256, 0, stream>>>(x_in, xbA, NNODE * DD / 4);

  const int NB = (NNODE + 255) / 256;  // 391
  hipMemsetAsync(deg, 0, (size_t)NNODE * 4, stream);
  count_kernel<<<(NEDGE + 255) / 256, 256, 0, stream>>>(eidx + NEDGE, deg);
  scan1_kernel<<<NB, 256, 0, stream>>>(deg, locex, bsum);
  scan2_kernel<<<1, 512, 0, stream>>>(bsum, NB);
  scan3_kernel<<<NB, 256, 0, stream>>>(locex, bsum, offs, cur);
  fill_kernel<<<(NEDGE + 255) / 256, 256, 0, stream>>>(eidx, eidx + NEDGE, cur, seid, ssrc);
  if (use_eab)
    gather_cvt_kernel<<<NEDGE / 4, 256, 0, stream>>>(ea_f, seid, eab, NEDGE);

  const int egrid = (NEDGE + 63) / 64;
  const int ngrid = (NNODE + 63) / 64;
  short* xin = xbA;
  short* xout = xbB;
  for (int l = 0; l < NLAY; ++l) {
    if (use_eab) {
      mlp_kernel<true, false><<<egrid, 512, SMEM, stream>>>(
          eab, nullptr, nullptr, nullptr, nullptr,
          we1t + l * 65536, we2t + l * 65536, e1b + l * DD,
          e2b + l * DD, elg + l * DD, elb + l * DD, efeat, nullptr,
          nullptr, NEDGE);
    } else {
      mlp_kernel<false, false><<<egrid, 512, SMEM, stream>>>(
          ea_f, seid, nullptr, nullptr, nullptr,
          we1t + l * 65536, we2t + l * 65536, e1b + l * DD,
          e2b + l * DD, elg + l * DD, elb + l * DD, efeat, nullptr,
          nullptr, NEDGE);
    }
    mlp_kernel<true, true><<<ngrid, 512, SMEM, stream>>>(
        efeat, nullptr, offs, ssrc, xin,
        wn1t + l * 65536, wn2t + l * 65536, n1b + l * DD,
        n2b + l * DD, nlg + l * DD, nlb + l * DD, nullptr,
        (l == NLAY - 1) ? x : nullptr, xout, NNODE);
    short* t = xin; xin = xout; xout = t;
  }
  (void)in_sizes; (void)n_in; (void)out_size; (void)ws_size;
}